// Round 3
// baseline (1651.102 us; speedup 1.0000x reference)
//
#include <hip/hip_runtime.h>

#define NN 50000
#define NE 800000

__device__ __forceinline__ float silu_f(float x) { return x / (1.0f + __expf(-x)); }

// ---------------------------------------------------------------------------
// K1: x_s = s @ W1_s ; x_v planar: x_v[n*96 + c*32 + o] = sum_u v[n][u][c]*W1_v[u][o]
// ---------------------------------------------------------------------------
__global__ __launch_bounds__(256) void k_node_transform(
    const float* __restrict__ node_feats,
    const float* __restrict__ W1_s,
    const float* __restrict__ W1_v,
    float* __restrict__ x_s,
    float* __restrict__ x_v)
{
    __shared__ float sW1s[32 * 32];
    __shared__ float sW1v[32 * 32];
    __shared__ float sfeat[8][128];
    int t = threadIdx.x;
    for (int i = t; i < 1024; i += 256) { sW1s[i] = W1_s[i]; sW1v[i] = W1_v[i]; }
    int nodeBase = blockIdx.x * 8;
    for (int i = t; i < 8 * 128; i += 256) {
        int nn = nodeBase + (i >> 7);
        sfeat[i >> 7][i & 127] = (nn < NN) ? node_feats[(long)nn * 128 + (i & 127)] : 0.0f;
    }
    __syncthreads();
    int g = t >> 5, o = t & 31;
    int n = nodeBase + g;
    if (n >= NN) return;
    float accs = 0.f, acc0 = 0.f, acc1 = 0.f, acc2 = 0.f;
#pragma unroll
    for (int u = 0; u < 32; ++u) {
        float su  = sfeat[g][u];
        float vu0 = sfeat[g][32 + u * 3 + 0];
        float vu1 = sfeat[g][32 + u * 3 + 1];
        float vu2 = sfeat[g][32 + u * 3 + 2];
        float ws = sW1s[u * 32 + o];
        float wv = sW1v[u * 32 + o];
        accs += su * ws;
        acc0 += vu0 * wv;
        acc1 += vu1 * wv;
        acc2 += vu2 * wv;
    }
    x_s[(long)n * 32 + o] = accs;
    x_v[(long)n * 96 +      o] = acc0;
    x_v[(long)n * 96 + 32 + o] = acc1;
    x_v[(long)n * 96 + 64 + o] = acc2;
}

// ---------------------------------------------------------------------------
// CSR build: histogram -> single-block scan -> fill
// ---------------------------------------------------------------------------
__global__ __launch_bounds__(256) void k_hist(const int* __restrict__ edge_dst,
                                              int* __restrict__ counts)
{
    int e = blockIdx.x * 256 + threadIdx.x;
    if (e < NE) atomicAdd(&counts[edge_dst[e]], 1);
}

__global__ __launch_bounds__(1024) void k_scan(const int* __restrict__ counts,
                                               int* __restrict__ row_ptr,
                                               int* __restrict__ cursor)
{
    __shared__ int wsum[16];
    __shared__ int carry_s;
    int t = threadIdx.x;
    int lane = t & 63, w = t >> 6;
    if (t == 0) carry_s = 0;
    __syncthreads();
    for (int base = 0; base < NN; base += 1024) {
        int i = base + t;
        int v = (i < NN) ? counts[i] : 0;
        int s = v;
#pragma unroll
        for (int d = 1; d < 64; d <<= 1) {
            int o = __shfl_up(s, d, 64);
            if (lane >= d) s += o;
        }
        if (lane == 63) wsum[w] = s;
        __syncthreads();
        if (w == 0) {
            int ws = (lane < 16) ? wsum[lane] : 0;
#pragma unroll
            for (int d = 1; d < 16; d <<= 1) {
                int o = __shfl_up(ws, d, 64);
                if (lane >= d) ws += o;
            }
            if (lane < 16) wsum[lane] = ws;
        }
        __syncthreads();
        int excl = (s - v) + ((w > 0) ? wsum[w - 1] : 0) + carry_s;
        if (i < NN) { row_ptr[i] = excl; cursor[i] = excl; }
        int total = wsum[15];
        __syncthreads();
        if (t == 0) carry_s += total;
        __syncthreads();
    }
    if (t == 0) row_ptr[NN] = carry_s;
}

__global__ __launch_bounds__(256) void k_fill(const int* __restrict__ edge_dst,
                                              int* __restrict__ cursor,
                                              int* __restrict__ edge_ids)
{
    int e = blockIdx.x * 256 + threadIdx.x;
    if (e < NE) {
        int slot = atomicAdd(&cursor[edge_dst[e]], 1);
        edge_ids[slot] = e;
    }
}

// ---------------------------------------------------------------------------
// w2t: plain transpose w2t[c*64+j] = fc_w2[j*160+c]
// ---------------------------------------------------------------------------
__global__ __launch_bounds__(256) void k_w2t(const float* __restrict__ fc_w2,
                                             float* __restrict__ w2t)
{
    int i = blockIdx.x * 256 + threadIdx.x;
    if (i < 10240) {
        int c = i >> 6, j = i & 63;
        w2t[i] = fc_w2[j * 160 + c];
    }
}

// ---------------------------------------------------------------------------
// k_edge_mlp: edge-major MLP for slots [row_ptr[n0], row_ptr[n1]).
// ONE EDGE PER THREAD in CSR-slot order; h[64] in registers; weights via
// wave-uniform (scalar) loads; output transposed through LDS -> coalesced
// stores into chunk-local wbuf[slot - base].
// ---------------------------------------------------------------------------
__global__ __launch_bounds__(256) void k_edge_mlp(
    const float* __restrict__ edge_embedding,
    const int*   __restrict__ edge_ids,
    const int*   __restrict__ row_ptr,
    int n0, int n1, long capEdges,
    const float* __restrict__ fc_w1,
    const float* __restrict__ fc_b1,
    const float* __restrict__ w2t,
    float* __restrict__ wbuf)
{
    int baseSlot = row_ptr[n0];
    int endSlot  = row_ptr[n1];
    long chunkE  = (long)(endSlot - baseSlot);
    if ((long)blockIdx.x * 256 >= chunkE) return;   // uniform block exit

    __shared__ float sch[256][33];   // +1 pad col
    int t = threadIdx.x;
    long eIdx = (long)blockIdx.x * 256 + t;         // chunk-local edge index
    long rIdx = (eIdx < chunkE) ? eIdx : (chunkE - 1);
    int e = edge_ids[baseSlot + rIdx];

    float em[8];
    *(float4*)&em[0] = *(const float4*)&edge_embedding[(long)e * 8];
    *(float4*)&em[4] = *(const float4*)&edge_embedding[(long)e * 8 + 4];

    float h[64];
#pragma unroll
    for (int j = 0; j < 64; ++j) {
        float a = fc_b1[j];
#pragma unroll
        for (int q = 0; q < 8; ++q) a += em[q] * fc_w1[q * 64 + j];
        h[j] = silu_f(a);
    }

    long blockBase = (long)blockIdx.x * 256;
#pragma unroll 1
    for (int cc = 0; cc < 160; cc += 32) {
#pragma unroll 2
        for (int c0 = 0; c0 < 32; c0 += 4) {
            float a0 = 0.f, a1 = 0.f, a2 = 0.f, a3 = 0.f;
            const float* wp = &w2t[(cc + c0) * 64];   // wave-uniform address
#pragma unroll
            for (int j = 0; j < 64; ++j) {
                float hj = h[j];
                a0 += hj * wp[j];
                a1 += hj * wp[64 + j];
                a2 += hj * wp[128 + j];
                a3 += hj * wp[192 + j];
            }
            sch[t][c0 + 0] = a0; sch[t][c0 + 1] = a1;
            sch[t][c0 + 2] = a2; sch[t][c0 + 3] = a3;
        }
        __syncthreads();
        for (int k = t; k < 256 * 32; k += 256) {
            int row = k >> 5, col = k & 31;
            long oe = blockBase + row;
            if (oe < chunkE && oe < capEdges)
                wbuf[oe * 160 + cc + col] = sch[row][col];
        }
        __syncthreads();
    }
}

// ---------------------------------------------------------------------------
// k_gather_s: nodes [n0, n1); stream precomputed w (chunk-local,
// slot-sequential), gather x, register-accumulate messages, fused epilogue.
// block = 256 = 8 groups x 32 lanes, group = one node. No block barriers.
// ---------------------------------------------------------------------------
__global__ __launch_bounds__(256) void k_gather_s(
    const float* __restrict__ edge_attrs,
    const int*   __restrict__ edge_src,
    const float* __restrict__ wbuf,
    const float* __restrict__ x_s,
    const float* __restrict__ x_v,
    const int*   __restrict__ row_ptr,
    const int*   __restrict__ edge_ids,
    int n0, int n1, long capEdges,
    const float* __restrict__ node_feats,
    const float* __restrict__ node_attrs,
    const float* __restrict__ W2_s,
    const float* __restrict__ W2_v,
    const float* __restrict__ Wsc_s,
    const float* __restrict__ Wsc_v,
    float* __restrict__ out)
{
    __shared__ __align__(16) float sfeat[8][144];
    __shared__ float asbuf[8][64];
    __shared__ float avbuf[8][288];

    int t = threadIdx.x;
    int g = t >> 5, lane = t & 31;
    int n = n0 + blockIdx.x * 8 + g;
    if (n >= n1 || n >= NN) return;

    int baseSlot = row_ptr[n0];
    int start = row_ptr[n];
    int end   = row_ptr[n + 1];

    float as0 = 0.f, as1 = 0.f;
    float av[9];
#pragma unroll
    for (int p = 0; p < 9; ++p) av[p] = 0.f;

    const float INV_SQRT3 = 0.5773502691896258f;
    const float INV_SQRT2 = 0.7071067811865476f;
    const float INV_NEI   = 0.25f;

    for (int i = start; i < end; i += 4) {
        int ne = end - i;
        int sl[4], eid[4], src[4];
#pragma unroll
        for (int k = 0; k < 4; ++k) sl[k] = (k < ne) ? (i + k) : i;
#pragma unroll
        for (int k = 0; k < 4; ++k) eid[k] = edge_ids[sl[k]];
#pragma unroll
        for (int k = 0; k < 4; ++k) src[k] = edge_src[eid[k]];
        float4 at[4];
#pragma unroll
        for (int k = 0; k < 4; ++k) at[k] = *(const float4*)&edge_attrs[(long)eid[k] * 4];
        float w00[4], w01[4], w10[4], w11s[4], w11v[4];
#pragma unroll
        for (int k = 0; k < 4; ++k) {
            long wi = (long)(sl[k] - baseSlot);
            if (wi >= capEdges) wi = capEdges - 1;
            const float* wp = &wbuf[wi * 160 + lane];
            w00[k] = wp[0]; w01[k] = wp[32]; w10[k] = wp[64];
            w11s[k] = wp[96]; w11v[k] = wp[128];
        }
        float xs[4], xv0[4], xv1[4], xv2[4];
#pragma unroll
        for (int k = 0; k < 4; ++k) {
            xs[k]  = x_s[(long)src[k] * 32 + lane];
            xv0[k] = x_v[(long)src[k] * 96 +      lane];
            xv1[k] = x_v[(long)src[k] * 96 + 32 + lane];
            xv2[k] = x_v[(long)src[k] * 96 + 64 + lane];
        }
#pragma unroll
        for (int k = 0; k < 4; ++k) {
            if (k >= ne) break;
            float4 a4 = at[k];
            as0 += w00[k] * xs[k] * a4.x;
            float dot = xv0[k] * a4.y + xv1[k] * a4.z + xv2[k] * a4.w;
            as1 += w11s[k] * dot * INV_SQRT3;
            float t01 = w01[k] * xs[k];
            av[0] += t01 * a4.y; av[1] += t01 * a4.z; av[2] += t01 * a4.w;
            float t10 = w10[k] * a4.x;
            av[3] += t10 * xv0[k]; av[4] += t10 * xv1[k]; av[5] += t10 * xv2[k];
            float k2 = w11v[k] * INV_SQRT2;
            av[6] += k2 * (xv1[k] * a4.w - xv2[k] * a4.z);
            av[7] += k2 * (xv2[k] * a4.y - xv0[k] * a4.w);
            av[8] += k2 * (xv0[k] * a4.z - xv1[k] * a4.y);
        }
    }

    asbuf[g][lane]      = as0 * INV_NEI;
    asbuf[g][32 + lane] = as1 * INV_NEI;
#pragma unroll
    for (int p = 0; p < 3; ++p)
#pragma unroll
        for (int c = 0; c < 3; ++c)
            avbuf[g][(p * 32 + lane) * 3 + c] = av[p * 3 + c] * INV_NEI;

    float* fb = &sfeat[g][0];
    *(float4*)&fb[lane * 4] = *(const float4*)&node_feats[(long)n * 128 + lane * 4];
    if (lane < 16) fb[128 + lane] = node_attrs[(long)n * 16 + lane];

    int o = lane;
    float ys0 = 0.f, ys1 = 0.f, yv0 = 0.f, yv1 = 0.f, yv2 = 0.f;

#pragma unroll 8
    for (int u = 0; u < 64; ++u) {
        float as = asbuf[g][u];
        ys0 += as * W2_s[u * 64 + o];
        ys1 += as * W2_s[u * 64 + 32 + o];
    }
#pragma unroll 8
    for (int u = 0; u < 96; ++u) {
        float wv = W2_v[u * 32 + o];
        yv0 += avbuf[g][u * 3 + 0] * wv;
        yv1 += avbuf[g][u * 3 + 1] * wv;
        yv2 += avbuf[g][u * 3 + 2] * wv;
    }

    float att[16];
#pragma unroll
    for (int a = 0; a < 16; ++a) att[a] = fb[128 + a];

    for (int u = 0; u < 32; ++u) {
        const float* Wsp = &Wsc_s[u * 1024 + o];
        const float* Wvp = &Wsc_v[u * 512 + o];
        float t0 = 0.f, t1 = 0.f, tv = 0.f;
#pragma unroll
        for (int a = 0; a < 16; ++a) {
            float aa = att[a];
            t0 += aa * Wsp[a * 64];
            t1 += aa * Wsp[a * 64 + 32];
            tv += aa * Wvp[a * 32];
        }
        float su = fb[u];
        ys0 += su * t0;
        ys1 += su * t1;
        float vv0 = fb[32 + u * 3 + 0];
        float vv1 = fb[32 + u * 3 + 1];
        float vv2 = fb[32 + u * 3 + 2];
        yv0 += vv0 * tv;
        yv1 += vv1 * tv;
        yv2 += vv2 * tv;
    }

    float os   = silu_f(ys0);
    float gate = silu_f(ys1);
    long base = (long)n * 128;
    out[base + o] = fb[o] + os;
    out[base + 32 + o * 3 + 0] = fb[32 + o * 3 + 0] + yv0 * gate;
    out[base + 32 + o * 3 + 1] = fb[32 + o * 3 + 1] + yv1 * gate;
    out[base + 32 + o * 3 + 2] = fb[32 + o * 3 + 2] + yv2 * gate;
}

// ---------------------------------------------------------------------------
// FALLBACK (ws too small even for chunked wbuf): Round-0 fused kernel.
// ---------------------------------------------------------------------------
__global__ __launch_bounds__(256) void k_gather_fused(
    const float* __restrict__ edge_embedding,
    const float* __restrict__ edge_attrs,
    const int*   __restrict__ edge_src,
    const float* __restrict__ fc_w1,
    const float* __restrict__ fc_b1,
    const float* __restrict__ fc_w2,
    const float* __restrict__ x_s,
    const float* __restrict__ x_v,
    const int*   __restrict__ row_ptr,
    const int*   __restrict__ edge_ids,
    const float* __restrict__ node_feats,
    const float* __restrict__ node_attrs,
    const float* __restrict__ W2_s,
    const float* __restrict__ W2_v,
    const float* __restrict__ Wsc_s,
    const float* __restrict__ Wsc_v,
    float* __restrict__ out)
{
    __shared__ __align__(16) float sw1[8 * 64];
    __shared__ float sb1[64];
    __shared__ __align__(16) float sw2[64 * 160];
    __shared__ __align__(16) float hbuf[8][256];
    __shared__ float asbuf[8][64];
    __shared__ float avbuf[8][288];

    int t = threadIdx.x;
    for (int i = t; i < 8 * 64; i += 256) sw1[i] = fc_w1[i];
    if (t < 64) sb1[t] = fc_b1[t];
    for (int i = t; i < 64 * 160; i += 256) sw2[i] = fc_w2[i];
    __syncthreads();

    int g = t >> 5, lane = t & 31;
    int n = blockIdx.x * 8 + g;
    if (n >= NN) return;

    int start = row_ptr[n];
    int end   = row_ptr[n + 1];

    float as0 = 0.f, as1 = 0.f;
    float av[9];
#pragma unroll
    for (int p = 0; p < 9; ++p) av[p] = 0.f;

    float* hb = &hbuf[g][0];
    const float INV_SQRT3 = 0.5773502691896258f;
    const float INV_SQRT2 = 0.7071067811865476f;
    const float INV_NEI   = 0.25f;

    for (int i = start; i < end; i += 4) {
        int ne = end - i;
        int eid[4];
#pragma unroll
        for (int k = 0; k < 4; ++k) eid[k] = edge_ids[(k < ne) ? (i + k) : i];
        float em[4][8];
#pragma unroll
        for (int k = 0; k < 4; ++k) {
            *(float4*)&em[k][0] = *(const float4*)&edge_embedding[(long)eid[k] * 8];
            *(float4*)&em[k][4] = *(const float4*)&edge_embedding[(long)eid[k] * 8 + 4];
        }
#pragma unroll
        for (int k = 0; k < 4; ++k) {
            float h0 = sb1[lane], h1 = sb1[lane + 32];
#pragma unroll
            for (int q = 0; q < 8; ++q) {
                float e = em[k][q];
                h0 += e * sw1[q * 64 + lane];
                h1 += e * sw1[q * 64 + lane + 32];
            }
            hb[k * 64 + lane]      = silu_f(h0);
            hb[k * 64 + 32 + lane] = silu_f(h1);
        }
        float acc[5][4];
#pragma unroll
        for (int p = 0; p < 5; ++p)
#pragma unroll
            for (int k = 0; k < 4; ++k) acc[p][k] = 0.f;

#pragma unroll 4
        for (int j = 0; j < 64; ++j) {
            const float* wr = &sw2[j * 160 + lane];
            float w0 = wr[0], w1 = wr[32], w2 = wr[64], w3 = wr[96], w4 = wr[128];
#pragma unroll
            for (int k = 0; k < 4; ++k) {
                float hj = hb[k * 64 + j];
                acc[0][k] += hj * w0;
                acc[1][k] += hj * w1;
                acc[2][k] += hj * w2;
                acc[3][k] += hj * w3;
                acc[4][k] += hj * w4;
            }
        }
#pragma unroll
        for (int k = 0; k < 4; ++k) {
            if (k >= ne) break;
            int e = eid[k];
            int src = edge_src[e];
            float4 at = *(const float4*)&edge_attrs[(long)e * 4];
            float xs  = x_s[(long)src * 32 + lane];
            float xv0 = x_v[(long)src * 96 +      lane];
            float xv1 = x_v[(long)src * 96 + 32 + lane];
            float xv2 = x_v[(long)src * 96 + 64 + lane];
            float w00 = acc[0][k], w01 = acc[1][k], w10 = acc[2][k];
            float w11s = acc[3][k], w11v = acc[4][k];
            as0 += w00 * xs * at.x;
            float dot = xv0 * at.y + xv1 * at.z + xv2 * at.w;
            as1 += w11s * dot * INV_SQRT3;
            float t01 = w01 * xs;
            av[0] += t01 * at.y; av[1] += t01 * at.z; av[2] += t01 * at.w;
            float t10 = w10 * at.x;
            av[3] += t10 * xv0; av[4] += t10 * xv1; av[5] += t10 * xv2;
            float k2 = w11v * INV_SQRT2;
            av[6] += k2 * (xv1 * at.w - xv2 * at.z);
            av[7] += k2 * (xv2 * at.y - xv0 * at.w);
            av[8] += k2 * (xv0 * at.z - xv1 * at.y);
        }
    }

    asbuf[g][lane]      = as0 * INV_NEI;
    asbuf[g][32 + lane] = as1 * INV_NEI;
#pragma unroll
    for (int p = 0; p < 3; ++p)
#pragma unroll
        for (int c = 0; c < 3; ++c)
            avbuf[g][(p * 32 + lane) * 3 + c] = av[p * 3 + c] * INV_NEI;

    *(float4*)&hb[lane * 4] = *(const float4*)&node_feats[(long)n * 128 + lane * 4];
    if (lane < 16) hb[128 + lane] = node_attrs[(long)n * 16 + lane];

    int o = lane;
    float ys0 = 0.f, ys1 = 0.f, yv0 = 0.f, yv1 = 0.f, yv2 = 0.f;
#pragma unroll 8
    for (int u = 0; u < 64; ++u) {
        float as = asbuf[g][u];
        ys0 += as * W2_s[u * 64 + o];
        ys1 += as * W2_s[u * 64 + 32 + o];
    }
#pragma unroll 8
    for (int u = 0; u < 96; ++u) {
        float wv = W2_v[u * 32 + o];
        yv0 += avbuf[g][u * 3 + 0] * wv;
        yv1 += avbuf[g][u * 3 + 1] * wv;
        yv2 += avbuf[g][u * 3 + 2] * wv;
    }
    float att[16];
#pragma unroll
    for (int a = 0; a < 16; ++a) att[a] = hb[128 + a];
    for (int u = 0; u < 32; ++u) {
        const float* Wsp = &Wsc_s[u * 1024 + o];
        const float* Wvp = &Wsc_v[u * 512 + o];
        float t0 = 0.f, t1 = 0.f, tv = 0.f;
#pragma unroll
        for (int a = 0; a < 16; ++a) {
            float aa = att[a];
            t0 += aa * Wsp[a * 64];
            t1 += aa * Wsp[a * 64 + 32];
            tv += aa * Wvp[a * 32];
        }
        float su = hb[u];
        ys0 += su * t0;
        ys1 += su * t1;
        float vv0 = hb[32 + u * 3 + 0];
        float vv1 = hb[32 + u * 3 + 1];
        float vv2 = hb[32 + u * 3 + 2];
        yv0 += vv0 * tv;
        yv1 += vv1 * tv;
        yv2 += vv2 * tv;
    }
    float os   = silu_f(ys0);
    float gate = silu_f(ys1);
    long base = (long)n * 128;
    out[base + o] = hb[o] + os;
    out[base + 32 + o * 3 + 0] = hb[32 + o * 3 + 0] + yv0 * gate;
    out[base + 32 + o * 3 + 1] = hb[32 + o * 3 + 1] + yv1 * gate;
    out[base + 32 + o * 3 + 2] = hb[32 + o * 3 + 2] + yv2 * gate;
}

// ---------------------------------------------------------------------------
extern "C" void kernel_launch(void* const* d_in, const int* in_sizes, int n_in,
                              void* d_out, int out_size, void* d_ws, size_t ws_size,
                              hipStream_t stream) {
    const float* node_feats     = (const float*)d_in[0];
    const float* node_attrs     = (const float*)d_in[1];
    const float* edge_embedding = (const float*)d_in[2];
    const float* edge_attrs     = (const float*)d_in[3];
    const int*   edge_src       = (const int*)d_in[4];
    const int*   edge_dst       = (const int*)d_in[5];
    const float* W1_s  = (const float*)d_in[6];
    const float* W1_v  = (const float*)d_in[7];
    const float* fc_w1 = (const float*)d_in[8];
    const float* fc_b1 = (const float*)d_in[9];
    const float* fc_w2 = (const float*)d_in[10];
    const float* W2_s  = (const float*)d_in[11];
    const float* W2_v  = (const float*)d_in[12];
    const float* Wsc_s = (const float*)d_in[13];
    const float* Wsc_v = (const float*)d_in[14];
    float* out = (float*)d_out;

    float* ws  = (float*)d_ws;
    float* x_s = ws;                       // NN*32 floats
    float* x_v = ws + (long)NN * 32;       // NN*96 floats (planar)
    int* ibase    = (int*)(ws + (long)NN * 128);
    int* counts   = ibase;                 // NN
    int* row_ptr  = ibase + NN;            // NN+1
    int* cursor   = ibase + 2 * NN + 1;    // NN
    int* edge_ids = ibase + 3 * NN + 1;    // NE

    long intWords = 3L * NN + 4 + NE;              // 16B-aligned tail
    float* w2t  = (float*)(ibase + intWords);      // 10240 floats
    float* wbuf = w2t + 10240;                     // chunked w buffer
    size_t baseWords = (size_t)NN * 128 + (size_t)intWords + 10240;

    // pick smallest chunk count whose safe per-chunk capacity fits
    long capEdges = 0;
    int nc = 0;
    if (ws_size / 4 > baseWords) {
        capEdges = (long)(ws_size / 4 - baseWords) / 160;
        for (int c = 1; c <= 16; ++c) {
            long per  = (NE + c - 1) / c;
            long need = per + per / 12 + 4096;     // ~8% + 4096 slack (>30 sigma)
            if (need <= capEdges) { nc = c; break; }
        }
    }

    hipMemsetAsync(counts, 0, (size_t)NN * sizeof(int), stream);
    k_hist<<<(NE + 255) / 256, 256, 0, stream>>>(edge_dst, counts);
    k_node_transform<<<(NN + 7) / 8, 256, 0, stream>>>(node_feats, W1_s, W1_v, x_s, x_v);
    k_scan<<<1, 1024, 0, stream>>>(counts, row_ptr, cursor);
    k_fill<<<(NE + 255) / 256, 256, 0, stream>>>(edge_dst, cursor, edge_ids);

    if (nc > 0) {
        k_w2t<<<40, 256, 0, stream>>>(fc_w2, w2t);
        long per   = (NE + nc - 1) / nc;
        long gridE = (per + per / 12 + 4096 + 255) / 256;
        int  npc   = (NN + nc - 1) / nc;
        for (int c = 0; c < nc; ++c) {
            int a = c * npc;
            int b = (a + npc < NN) ? (a + npc) : NN;
            if (a >= b) break;
            k_edge_mlp<<<(int)gridE, 256, 0, stream>>>(edge_embedding, edge_ids, row_ptr,
                                                       a, b, capEdges,
                                                       fc_w1, fc_b1, w2t, wbuf);
            k_gather_s<<<(b - a + 7) / 8, 256, 0, stream>>>(edge_attrs, edge_src, wbuf,
                                                            x_s, x_v, row_ptr, edge_ids,
                                                            a, b, capEdges,
                                                            node_feats, node_attrs,
                                                            W2_s, W2_v, Wsc_s, Wsc_v, out);
        }
    } else {
        k_gather_fused<<<(NN + 7) / 8, 256, 0, stream>>>(edge_embedding, edge_attrs, edge_src,
                                                         fc_w1, fc_b1, fc_w2, x_s, x_v,
                                                         row_ptr, edge_ids,
                                                         node_feats, node_attrs,
                                                         W2_s, W2_v, Wsc_s, Wsc_v, out);
    }
}

// Round 4
// 980.976 us; speedup vs baseline: 1.6831x; 1.6831x over previous
//
#include <hip/hip_runtime.h>

#define NN 50000
#define NE 800000

__device__ __forceinline__ float silu_f(float x) { return x / (1.0f + __expf(-x)); }

// ---------------------------------------------------------------------------
// K1: xf[n][o] = float4( (s@W1_s)[o], xv0[o], xv1[o], xv2[o] )
//   xv_c[o] = sum_u v[n][u][c] * W1_v[u][o]
// One float4 per (node, lane) -> k_gather does ONE 16B gather per edge-lane.
// ---------------------------------------------------------------------------
__global__ __launch_bounds__(256) void k_node_transform(
    const float* __restrict__ node_feats,
    const float* __restrict__ W1_s,
    const float* __restrict__ W1_v,
    float* __restrict__ xf)
{
    __shared__ float sW1s[32 * 32];
    __shared__ float sW1v[32 * 32];
    __shared__ float sfeat[8][128];
    int t = threadIdx.x;
    for (int i = t; i < 1024; i += 256) { sW1s[i] = W1_s[i]; sW1v[i] = W1_v[i]; }
    int nodeBase = blockIdx.x * 8;
    for (int i = t; i < 8 * 128; i += 256) {
        int nn = nodeBase + (i >> 7);
        sfeat[i >> 7][i & 127] = (nn < NN) ? node_feats[(long)nn * 128 + (i & 127)] : 0.0f;
    }
    __syncthreads();
    int g = t >> 5, o = t & 31;
    int n = nodeBase + g;
    if (n >= NN) return;
    float accs = 0.f, acc0 = 0.f, acc1 = 0.f, acc2 = 0.f;
#pragma unroll
    for (int u = 0; u < 32; ++u) {
        float su  = sfeat[g][u];
        float vu0 = sfeat[g][32 + u * 3 + 0];
        float vu1 = sfeat[g][32 + u * 3 + 1];
        float vu2 = sfeat[g][32 + u * 3 + 2];
        float ws = sW1s[u * 32 + o];
        float wv = sW1v[u * 32 + o];
        accs += su * ws;
        acc0 += vu0 * wv;
        acc1 += vu1 * wv;
        acc2 += vu2 * wv;
    }
    float4 r; r.x = accs; r.y = acc0; r.z = acc1; r.w = acc2;
    *(float4*)&xf[((long)n * 32 + o) * 4] = r;
}

// ---------------------------------------------------------------------------
// CSR build: histogram -> single-block scan -> fill
// ---------------------------------------------------------------------------
__global__ __launch_bounds__(256) void k_hist(const int* __restrict__ edge_dst,
                                              int* __restrict__ counts)
{
    int e = blockIdx.x * 256 + threadIdx.x;
    if (e < NE) atomicAdd(&counts[edge_dst[e]], 1);
}

__global__ __launch_bounds__(1024) void k_scan(const int* __restrict__ counts,
                                               int* __restrict__ row_ptr,
                                               int* __restrict__ cursor)
{
    __shared__ int wsum[16];
    __shared__ int carry_s;
    int t = threadIdx.x;
    int lane = t & 63, w = t >> 6;
    if (t == 0) carry_s = 0;
    __syncthreads();
    for (int base = 0; base < NN; base += 1024) {
        int i = base + t;
        int v = (i < NN) ? counts[i] : 0;
        int s = v;
#pragma unroll
        for (int d = 1; d < 64; d <<= 1) {
            int o = __shfl_up(s, d, 64);
            if (lane >= d) s += o;
        }
        if (lane == 63) wsum[w] = s;
        __syncthreads();
        if (w == 0) {
            int ws = (lane < 16) ? wsum[lane] : 0;
#pragma unroll
            for (int d = 1; d < 16; d <<= 1) {
                int o = __shfl_up(ws, d, 64);
                if (lane >= d) ws += o;
            }
            if (lane < 16) wsum[lane] = ws;
        }
        __syncthreads();
        int excl = (s - v) + ((w > 0) ? wsum[w - 1] : 0) + carry_s;
        if (i < NN) { row_ptr[i] = excl; cursor[i] = excl; }
        int total = wsum[15];
        __syncthreads();
        if (t == 0) carry_s += total;
        __syncthreads();
    }
    if (t == 0) row_ptr[NN] = carry_s;
}

__global__ __launch_bounds__(256) void k_fill(const int* __restrict__ edge_dst,
                                              int* __restrict__ cursor,
                                              int* __restrict__ edge_ids)
{
    int e = blockIdx.x * 256 + threadIdx.x;
    if (e < NE) {
        int slot = atomicAdd(&cursor[edge_dst[e]], 1);
        edge_ids[slot] = e;
    }
}

// ---------------------------------------------------------------------------
// k_gather_t: fused per-dst-node kernel (edge MLP + messages + epilogue).
// block = 256 = 8 groups x 32 lanes, group = one node, 4-edge inner blocking.
//
// GEMV fix vs R0: fc_w2 staged TRANSPOSED in LDS as sw2t[c][j], row stride 68
// (68 mod 32 = 4 -> ds_read_b128 across 32 lanes = conflict-free 4-pass).
// Inner loop reads 4 j's at a time: 5 w-b128 + 4 h-b128 per j-block
// -> 144 DS instructions per 4-edge iter (was 576 scalar b32).
// Both wave halves (2 groups) read identical w addresses -> broadcast.
// ---------------------------------------------------------------------------
__global__ __launch_bounds__(256) void k_gather_t(
    const float* __restrict__ edge_embedding,
    const float* __restrict__ edge_attrs,
    const int*   __restrict__ edge_src,
    const float* __restrict__ fc_w1,
    const float* __restrict__ fc_b1,
    const float* __restrict__ fc_w2,
    const float* __restrict__ xf,
    const int*   __restrict__ row_ptr,
    const int*   __restrict__ edge_ids,
    const float* __restrict__ node_feats,
    const float* __restrict__ node_attrs,
    const float* __restrict__ W2_s,
    const float* __restrict__ W2_v,
    const float* __restrict__ Wsc_s,
    const float* __restrict__ Wsc_v,
    float* __restrict__ out)
{
    __shared__ __align__(16) float sw1[8 * 64];     // 2 KB
    __shared__ float sb1[64];
    __shared__ __align__(16) float sw2t[160 * 68];  // 42.5 KB transposed, pad 68
    __shared__ __align__(16) float hbuf[8][256];    // 8 KB (4 edges x 64 h) / reused
    __shared__ float asbuf[8][64];                  // 2 KB
    __shared__ float avbuf[8][288];                 // 9 KB

    int t = threadIdx.x;
    for (int i = t; i < 8 * 64; i += 256) sw1[i] = fc_w1[i];
    if (t < 64) sb1[t] = fc_b1[t];
    // coalesced read of fc_w2 (consecutive i -> consecutive c, same j),
    // scattered LDS write (cheap, one-time)
    for (int i = t; i < 64 * 160; i += 256) {
        int j = i / 160, c = i - j * 160;
        sw2t[c * 68 + j] = fc_w2[i];
    }
    __syncthreads();

    int g = t >> 5, lane = t & 31;
    int n = blockIdx.x * 8 + g;
    if (n >= NN) return;

    int start = row_ptr[n];
    int end   = row_ptr[n + 1];

    float as0 = 0.f, as1 = 0.f;
    float av[9];
#pragma unroll
    for (int p = 0; p < 9; ++p) av[p] = 0.f;

    float* hb = &hbuf[g][0];
    const float4* xf4 = (const float4*)xf;
    const float INV_SQRT3 = 0.5773502691896258f;
    const float INV_SQRT2 = 0.7071067811865476f;
    const float INV_NEI   = 0.25f;

    for (int i = start; i < end; i += 4) {
        int ne = end - i;          // >= 1
        int eid[4];
#pragma unroll
        for (int k = 0; k < 4; ++k) eid[k] = edge_ids[(k < ne) ? (i + k) : i];

        // ---- issue ALL per-edge global loads up front (hidden+GEMV hides them)
        int srcv[4];
#pragma unroll
        for (int k = 0; k < 4; ++k) srcv[k] = edge_src[eid[k]];
        float4 at[4];
#pragma unroll
        for (int k = 0; k < 4; ++k) at[k] = *(const float4*)&edge_attrs[(long)eid[k] * 4];
        float4 xv[4];
#pragma unroll
        for (int k = 0; k < 4; ++k) xv[k] = xf4[(long)srcv[k] * 32 + lane];
        float em[4][8];
#pragma unroll
        for (int k = 0; k < 4; ++k) {
            *(float4*)&em[k][0] = *(const float4*)&edge_embedding[(long)eid[k] * 8];
            *(float4*)&em[k][4] = *(const float4*)&edge_embedding[(long)eid[k] * 8 + 4];
        }

        // ---- hidden layer for 4 edges (dummies duplicate edge 0: safe values)
#pragma unroll
        for (int k = 0; k < 4; ++k) {
            float h0 = sb1[lane], h1 = sb1[lane + 32];
#pragma unroll
            for (int q = 0; q < 8; ++q) {
                float e = em[k][q];
                h0 += e * sw1[q * 64 + lane];
                h1 += e * sw1[q * 64 + lane + 32];
            }
            hb[k * 64 + lane]      = silu_f(h0);
            hb[k * 64 + 32 + lane] = silu_f(h1);
        }
        // same-wave LDS RAW: in-order DS pipe + compiler waitcnt; no barrier
        // (barrier here would be illegal: divergent trip counts across groups)

        // ---- w = h @ fc_w2 : vectorized over j (b128 reads, conflict-free)
        float acc[5][4];
#pragma unroll
        for (int p = 0; p < 5; ++p)
#pragma unroll
            for (int k = 0; k < 4; ++k) acc[p][k] = 0.f;

#pragma unroll 2
        for (int jb = 0; jb < 16; ++jb) {
            float4 w0 = *(const float4*)&sw2t[(0 * 32 + lane) * 68 + jb * 4];
            float4 w1 = *(const float4*)&sw2t[(1 * 32 + lane) * 68 + jb * 4];
            float4 w2 = *(const float4*)&sw2t[(2 * 32 + lane) * 68 + jb * 4];
            float4 w3 = *(const float4*)&sw2t[(3 * 32 + lane) * 68 + jb * 4];
            float4 w4 = *(const float4*)&sw2t[(4 * 32 + lane) * 68 + jb * 4];
#pragma unroll
            for (int k = 0; k < 4; ++k) {
                float4 h4 = *(const float4*)&hb[k * 64 + jb * 4];
                acc[0][k] += h4.x * w0.x + h4.y * w0.y + h4.z * w0.z + h4.w * w0.w;
                acc[1][k] += h4.x * w1.x + h4.y * w1.y + h4.z * w1.z + h4.w * w1.w;
                acc[2][k] += h4.x * w2.x + h4.y * w2.y + h4.z * w2.z + h4.w * w2.w;
                acc[3][k] += h4.x * w3.x + h4.y * w3.y + h4.z * w3.z + h4.w * w3.w;
                acc[4][k] += h4.x * w4.x + h4.y * w4.y + h4.z * w4.z + h4.w * w4.w;
            }
        }

        // ---- messages, register accumulate
#pragma unroll
        for (int k = 0; k < 4; ++k) {
            if (k >= ne) break;
            float4 a4 = at[k];
            float xs  = xv[k].x;
            float xv0 = xv[k].y, xv1 = xv[k].z, xv2 = xv[k].w;
            float w00 = acc[0][k], w01 = acc[1][k], w10 = acc[2][k];
            float w11s = acc[3][k], w11v = acc[4][k];

            as0 += w00 * xs * a4.x;
            float dot = xv0 * a4.y + xv1 * a4.z + xv2 * a4.w;
            as1 += w11s * dot * INV_SQRT3;
            float t01 = w01 * xs;
            av[0] += t01 * a4.y; av[1] += t01 * a4.z; av[2] += t01 * a4.w;
            float t10 = w10 * a4.x;
            av[3] += t10 * xv0; av[4] += t10 * xv1; av[5] += t10 * xv2;
            float k2 = w11v * INV_SQRT2;
            av[6] += k2 * (xv1 * a4.w - xv2 * a4.z);
            av[7] += k2 * (xv2 * a4.y - xv0 * a4.w);
            av[8] += k2 * (xv0 * a4.z - xv1 * a4.y);
        }
    }

    // ---- stage accumulators (group-private LDS, same-wave only)
    asbuf[g][lane]      = as0 * INV_NEI;
    asbuf[g][32 + lane] = as1 * INV_NEI;
#pragma unroll
    for (int p = 0; p < 3; ++p)
#pragma unroll
        for (int c = 0; c < 3; ++c)
            avbuf[g][(p * 32 + lane) * 3 + c] = av[p * 3 + c] * INV_NEI;

    // ---- stage this node's feats + attrs into hbuf (reuse)
    *(float4*)&hb[lane * 4] = *(const float4*)&node_feats[(long)n * 128 + lane * 4];
    if (lane < 16) hb[128 + lane] = node_attrs[(long)n * 16 + lane];

    // ---- fused epilogue: W2 GEMVs + Wsc bilinear (t-form) + gate + residual
    int o = lane;
    float ys0 = 0.f, ys1 = 0.f, yv0 = 0.f, yv1 = 0.f, yv2 = 0.f;

#pragma unroll 8
    for (int u = 0; u < 64; ++u) {
        float as = asbuf[g][u];
        ys0 += as * W2_s[u * 64 + o];
        ys1 += as * W2_s[u * 64 + 32 + o];
    }
#pragma unroll 8
    for (int u = 0; u < 96; ++u) {
        float wv = W2_v[u * 32 + o];
        yv0 += avbuf[g][u * 3 + 0] * wv;
        yv1 += avbuf[g][u * 3 + 1] * wv;
        yv2 += avbuf[g][u * 3 + 2] * wv;
    }

    float att[16];
#pragma unroll
    for (int a = 0; a < 16; ++a) att[a] = hb[128 + a];

    for (int u = 0; u < 32; ++u) {
        const float* Wsp = &Wsc_s[u * 1024 + o];
        const float* Wvp = &Wsc_v[u * 512 + o];
        float t0 = 0.f, t1 = 0.f, tv = 0.f;
#pragma unroll
        for (int a = 0; a < 16; ++a) {
            float aa = att[a];
            t0 += aa * Wsp[a * 64];
            t1 += aa * Wsp[a * 64 + 32];
            tv += aa * Wvp[a * 32];
        }
        float su = hb[u];
        ys0 += su * t0;
        ys1 += su * t1;
        float vv0 = hb[32 + u * 3 + 0];
        float vv1 = hb[32 + u * 3 + 1];
        float vv2 = hb[32 + u * 3 + 2];
        yv0 += vv0 * tv;
        yv1 += vv1 * tv;
        yv2 += vv2 * tv;
    }

    float os   = silu_f(ys0);
    float gate = silu_f(ys1);
    long base = (long)n * 128;
    out[base + o] = hb[o] + os;
    out[base + 32 + o * 3 + 0] = hb[32 + o * 3 + 0] + yv0 * gate;
    out[base + 32 + o * 3 + 1] = hb[32 + o * 3 + 1] + yv1 * gate;
    out[base + 32 + o * 3 + 2] = hb[32 + o * 3 + 2] + yv2 * gate;
}

// ---------------------------------------------------------------------------
extern "C" void kernel_launch(void* const* d_in, const int* in_sizes, int n_in,
                              void* d_out, int out_size, void* d_ws, size_t ws_size,
                              hipStream_t stream) {
    const float* node_feats     = (const float*)d_in[0];
    const float* node_attrs     = (const float*)d_in[1];
    const float* edge_embedding = (const float*)d_in[2];
    const float* edge_attrs     = (const float*)d_in[3];
    const int*   edge_src       = (const int*)d_in[4];
    const int*   edge_dst       = (const int*)d_in[5];
    const float* W1_s  = (const float*)d_in[6];
    const float* W1_v  = (const float*)d_in[7];
    const float* fc_w1 = (const float*)d_in[8];
    const float* fc_b1 = (const float*)d_in[9];
    const float* fc_w2 = (const float*)d_in[10];
    const float* W2_s  = (const float*)d_in[11];
    const float* W2_v  = (const float*)d_in[12];
    const float* Wsc_s = (const float*)d_in[13];
    const float* Wsc_v = (const float*)d_in[14];
    float* out = (float*)d_out;

    float* ws  = (float*)d_ws;
    float* xf  = ws;                       // NN*32 float4 = NN*128 floats
    int* ibase    = (int*)(ws + (long)NN * 128);
    int* counts   = ibase;                 // NN
    int* row_ptr  = ibase + NN;            // NN+1
    int* cursor   = ibase + 2 * NN + 1;    // NN
    int* edge_ids = ibase + 3 * NN + 1;    // NE

    hipMemsetAsync(counts, 0, (size_t)NN * sizeof(int), stream);
    k_hist<<<(NE + 255) / 256, 256, 0, stream>>>(edge_dst, counts);
    k_node_transform<<<(NN + 7) / 8, 256, 0, stream>>>(node_feats, W1_s, W1_v, xf);
    k_scan<<<1, 1024, 0, stream>>>(counts, row_ptr, cursor);
    k_fill<<<(NE + 255) / 256, 256, 0, stream>>>(edge_dst, cursor, edge_ids);
    k_gather_t<<<(NN + 7) / 8, 256, 0, stream>>>(edge_embedding, edge_attrs, edge_src,
                                                 fc_w1, fc_b1, fc_w2, xf,
                                                 row_ptr, edge_ids,
                                                 node_feats, node_attrs,
                                                 W2_s, W2_v, Wsc_s, Wsc_v, out);
}

// Round 5
// 921.583 us; speedup vs baseline: 1.7916x; 1.0644x over previous
//
#include <hip/hip_runtime.h>

#define NN 50000
#define NE 800000
// NN % 8 == 0  ->  grid of NN/8 blocks, 8 nodes/block, NO early returns
// (required: k_gather_t has a post-loop __syncthreads)

__device__ __forceinline__ float silu_f(float x) { return x / (1.0f + __expf(-x)); }

// ---------------------------------------------------------------------------
// K1: xf[n][o] = float4( (s@W1_s)[o], xv0[o], xv1[o], xv2[o] )
// One float4 per (node, lane) -> k_gather does ONE 16B gather per edge-lane.
// ---------------------------------------------------------------------------
__global__ __launch_bounds__(256) void k_node_transform(
    const float* __restrict__ node_feats,
    const float* __restrict__ W1_s,
    const float* __restrict__ W1_v,
    float* __restrict__ xf)
{
    __shared__ float sW1s[32 * 32];
    __shared__ float sW1v[32 * 32];
    __shared__ float sfeat[8][128];
    int t = threadIdx.x;
    for (int i = t; i < 1024; i += 256) { sW1s[i] = W1_s[i]; sW1v[i] = W1_v[i]; }
    int nodeBase = blockIdx.x * 8;
    for (int i = t; i < 8 * 128; i += 256) {
        int nn = nodeBase + (i >> 7);
        sfeat[i >> 7][i & 127] = (nn < NN) ? node_feats[(long)nn * 128 + (i & 127)] : 0.0f;
    }
    __syncthreads();
    int g = t >> 5, o = t & 31;
    int n = nodeBase + g;
    if (n >= NN) return;
    float accs = 0.f, acc0 = 0.f, acc1 = 0.f, acc2 = 0.f;
#pragma unroll
    for (int u = 0; u < 32; ++u) {
        float su  = sfeat[g][u];
        float vu0 = sfeat[g][32 + u * 3 + 0];
        float vu1 = sfeat[g][32 + u * 3 + 1];
        float vu2 = sfeat[g][32 + u * 3 + 2];
        float ws = sW1s[u * 32 + o];
        float wv = sW1v[u * 32 + o];
        accs += su * ws;
        acc0 += vu0 * wv;
        acc1 += vu1 * wv;
        acc2 += vu2 * wv;
    }
    float4 r; r.x = accs; r.y = acc0; r.z = acc1; r.w = acc2;
    *(float4*)&xf[((long)n * 32 + o) * 4] = r;
}

// ---------------------------------------------------------------------------
// CSR build: histogram -> single-block scan -> fill
// ---------------------------------------------------------------------------
__global__ __launch_bounds__(256) void k_hist(const int* __restrict__ edge_dst,
                                              int* __restrict__ counts)
{
    int e = blockIdx.x * 256 + threadIdx.x;
    if (e < NE) atomicAdd(&counts[edge_dst[e]], 1);
}

__global__ __launch_bounds__(1024) void k_scan(const int* __restrict__ counts,
                                               int* __restrict__ row_ptr,
                                               int* __restrict__ cursor)
{
    __shared__ int wsum[16];
    __shared__ int carry_s;
    int t = threadIdx.x;
    int lane = t & 63, w = t >> 6;
    if (t == 0) carry_s = 0;
    __syncthreads();
    for (int base = 0; base < NN; base += 1024) {
        int i = base + t;
        int v = (i < NN) ? counts[i] : 0;
        int s = v;
#pragma unroll
        for (int d = 1; d < 64; d <<= 1) {
            int o = __shfl_up(s, d, 64);
            if (lane >= d) s += o;
        }
        if (lane == 63) wsum[w] = s;
        __syncthreads();
        if (w == 0) {
            int ws = (lane < 16) ? wsum[lane] : 0;
#pragma unroll
            for (int d = 1; d < 16; d <<= 1) {
                int o = __shfl_up(ws, d, 64);
                if (lane >= d) ws += o;
            }
            if (lane < 16) wsum[lane] = ws;
        }
        __syncthreads();
        int excl = (s - v) + ((w > 0) ? wsum[w - 1] : 0) + carry_s;
        if (i < NN) { row_ptr[i] = excl; cursor[i] = excl; }
        int total = wsum[15];
        __syncthreads();
        if (t == 0) carry_s += total;
        __syncthreads();
    }
    if (t == 0) row_ptr[NN] = carry_s;
}

__global__ __launch_bounds__(256) void k_fill(const int* __restrict__ edge_dst,
                                              int* __restrict__ cursor,
                                              int* __restrict__ edge_ids)
{
    int e = blockIdx.x * 256 + threadIdx.x;
    if (e < NE) {
        int slot = atomicAdd(&cursor[edge_dst[e]], 1);
        edge_ids[slot] = e;
    }
}

// ---------------------------------------------------------------------------
// k_gather_t: fused per-dst-node kernel (edge MLP + messages + epilogue).
// block = 256 = 8 groups x 32 lanes, group = one node, 4-edge inner blocking.
//
// LDS budget (51.5 KB -> 3 blocks/CU, was 65.5 KB -> 2):
//   - fc_w1/fc_b1 hoisted to 18 loop-invariant REGISTERS (no LDS, and
//     removes 64 ds_read_b32 per 4-edge iter from the hidden layer)
//   - sw2t [160][68] transposed fc_w2 (stride 68: 16B-aligned, bank-balanced
//     b128 reads); after the edge loop + block barrier the weights are dead
//     and sw2t is REUSED as epilogue as/av scratch (NN%8==0 -> no early
//     returns -> the post-loop __syncthreads is legal)
//   - hbuf [8][256] h-exchange / feats+attrs reuse
// __launch_bounds__(256,3): VGPR cap ~170 (3 waves/SIMD); est. ~146 used.
// ---------------------------------------------------------------------------
__global__ __launch_bounds__(256, 3) void k_gather_t(
    const float* __restrict__ edge_embedding,
    const float* __restrict__ edge_attrs,
    const int*   __restrict__ edge_src,
    const float* __restrict__ fc_w1,
    const float* __restrict__ fc_b1,
    const float* __restrict__ fc_w2,
    const float* __restrict__ xf,
    const int*   __restrict__ row_ptr,
    const int*   __restrict__ edge_ids,
    const float* __restrict__ node_feats,
    const float* __restrict__ node_attrs,
    const float* __restrict__ W2_s,
    const float* __restrict__ W2_v,
    const float* __restrict__ Wsc_s,
    const float* __restrict__ Wsc_v,
    float* __restrict__ out)
{
    __shared__ __align__(16) float sw2t[160 * 68];  // 42.5 KB; epilogue scratch after barrier
    __shared__ __align__(16) float hbuf[8][256];    // 8 KB

    int t = threadIdx.x;
    // coalesced read of fc_w2 (consecutive i -> consecutive c, same j),
    // scattered LDS write (one-time)
    for (int i = t; i < 64 * 160; i += 256) {
        int j = i / 160, c = i - j * 160;
        sw2t[c * 68 + j] = fc_w2[i];
    }
    __syncthreads();

    int g = t >> 5, lane = t & 31;
    int n = blockIdx.x * 8 + g;      // NN % 8 == 0: always < NN

    // ---- loop-invariant first-layer weights in registers
    float w1a[8], w1b[8];
#pragma unroll
    for (int q = 0; q < 8; ++q) {
        w1a[q] = fc_w1[q * 64 + lane];
        w1b[q] = fc_w1[q * 64 + 32 + lane];
    }
    float b1a = fc_b1[lane], b1b = fc_b1[32 + lane];

    int start = row_ptr[n];
    int end   = row_ptr[n + 1];

    float as0 = 0.f, as1 = 0.f;
    float av[9];
#pragma unroll
    for (int p = 0; p < 9; ++p) av[p] = 0.f;

    float* hb = &hbuf[g][0];
    const float4* xf4 = (const float4*)xf;
    const float INV_SQRT3 = 0.5773502691896258f;
    const float INV_SQRT2 = 0.7071067811865476f;
    const float INV_NEI   = 0.25f;

    for (int i = start; i < end; i += 4) {
        int ne = end - i;          // >= 1
        int eid[4];
#pragma unroll
        for (int k = 0; k < 4; ++k) eid[k] = edge_ids[(k < ne) ? (i + k) : i];

        // ---- issue ALL per-edge global loads up front (hidden+GEMV hides them)
        int srcv[4];
#pragma unroll
        for (int k = 0; k < 4; ++k) srcv[k] = edge_src[eid[k]];
        float4 at[4];
#pragma unroll
        for (int k = 0; k < 4; ++k) at[k] = *(const float4*)&edge_attrs[(long)eid[k] * 4];
        float4 xv[4];
#pragma unroll
        for (int k = 0; k < 4; ++k) xv[k] = xf4[(long)srcv[k] * 32 + lane];
        float em[4][8];
#pragma unroll
        for (int k = 0; k < 4; ++k) {
            *(float4*)&em[k][0] = *(const float4*)&edge_embedding[(long)eid[k] * 8];
            *(float4*)&em[k][4] = *(const float4*)&edge_embedding[(long)eid[k] * 8 + 4];
        }

        // ---- hidden layer for 4 edges (register weights, dummies safe)
#pragma unroll
        for (int k = 0; k < 4; ++k) {
            float h0 = b1a, h1 = b1b;
#pragma unroll
            for (int q = 0; q < 8; ++q) {
                float e = em[k][q];
                h0 += e * w1a[q];
                h1 += e * w1b[q];
            }
            hb[k * 64 + lane]      = silu_f(h0);
            hb[k * 64 + 32 + lane] = silu_f(h1);
        }
        // same-wave LDS RAW: in-order DS pipe + compiler waitcnt; no barrier
        // (barrier inside the loop would be illegal: divergent trip counts)

        // ---- w = h @ fc_w2 : vectorized over j (b128 reads, bank-balanced)
        float acc[5][4];
#pragma unroll
        for (int p = 0; p < 5; ++p)
#pragma unroll
            for (int k = 0; k < 4; ++k) acc[p][k] = 0.f;

#pragma unroll 2
        for (int jb = 0; jb < 16; ++jb) {
            float4 w0 = *(const float4*)&sw2t[(0 * 32 + lane) * 68 + jb * 4];
            float4 w1 = *(const float4*)&sw2t[(1 * 32 + lane) * 68 + jb * 4];
            float4 w2 = *(const float4*)&sw2t[(2 * 32 + lane) * 68 + jb * 4];
            float4 w3 = *(const float4*)&sw2t[(3 * 32 + lane) * 68 + jb * 4];
            float4 w4 = *(const float4*)&sw2t[(4 * 32 + lane) * 68 + jb * 4];
#pragma unroll
            for (int k = 0; k < 4; ++k) {
                float4 h4 = *(const float4*)&hb[k * 64 + jb * 4];
                acc[0][k] += h4.x * w0.x + h4.y * w0.y + h4.z * w0.z + h4.w * w0.w;
                acc[1][k] += h4.x * w1.x + h4.y * w1.y + h4.z * w1.z + h4.w * w1.w;
                acc[2][k] += h4.x * w2.x + h4.y * w2.y + h4.z * w2.z + h4.w * w2.w;
                acc[3][k] += h4.x * w3.x + h4.y * w3.y + h4.z * w3.z + h4.w * w3.w;
                acc[4][k] += h4.x * w4.x + h4.y * w4.y + h4.z * w4.z + h4.w * w4.w;
            }
        }

        // ---- messages, register accumulate
#pragma unroll
        for (int k = 0; k < 4; ++k) {
            if (k >= ne) break;
            float4 a4 = at[k];
            float xs  = xv[k].x;
            float xv0 = xv[k].y, xv1 = xv[k].z, xv2 = xv[k].w;
            float w00 = acc[0][k], w01 = acc[1][k], w10 = acc[2][k];
            float w11s = acc[3][k], w11v = acc[4][k];

            as0 += w00 * xs * a4.x;
            float dot = xv0 * a4.y + xv1 * a4.z + xv2 * a4.w;
            as1 += w11s * dot * INV_SQRT3;
            float t01 = w01 * xs;
            av[0] += t01 * a4.y; av[1] += t01 * a4.z; av[2] += t01 * a4.w;
            float t10 = w10 * a4.x;
            av[3] += t10 * xv0; av[4] += t10 * xv1; av[5] += t10 * xv2;
            float k2 = w11v * INV_SQRT2;
            av[6] += k2 * (xv1 * a4.w - xv2 * a4.z);
            av[7] += k2 * (xv2 * a4.y - xv0 * a4.w);
            av[8] += k2 * (xv0 * a4.z - xv1 * a4.y);
        }
    }

    // ---- weights are dead; reuse sw2t as epilogue scratch. All 256 threads
    // reach this barrier (NN%8==0 -> no early return; loop always exits).
    __syncthreads();
    float* epi = sw2t + (g << 9);   // 512 floats/group: as[64] + av[288]

    epi[lane]      = as0 * INV_NEI;
    epi[32 + lane] = as1 * INV_NEI;
#pragma unroll
    for (int p = 0; p < 3; ++p)
#pragma unroll
        for (int c = 0; c < 3; ++c)
            epi[64 + (p * 32 + lane) * 3 + c] = av[p * 3 + c] * INV_NEI;

    // ---- stage this node's feats + attrs into hbuf (reuse)
    *(float4*)&hb[lane * 4] = *(const float4*)&node_feats[(long)n * 128 + lane * 4];
    if (lane < 16) hb[128 + lane] = node_attrs[(long)n * 16 + lane];

    // ---- fused epilogue: W2 GEMVs + Wsc bilinear (t-form) + gate + residual
    int o = lane;
    float ys0 = 0.f, ys1 = 0.f, yv0 = 0.f, yv1 = 0.f, yv2 = 0.f;

#pragma unroll 8
    for (int u = 0; u < 64; ++u) {
        float as = epi[u];
        ys0 += as * W2_s[u * 64 + o];
        ys1 += as * W2_s[u * 64 + 32 + o];
    }
#pragma unroll 8
    for (int u = 0; u < 96; ++u) {
        float wv = W2_v[u * 32 + o];
        yv0 += epi[64 + u * 3 + 0] * wv;
        yv1 += epi[64 + u * 3 + 1] * wv;
        yv2 += epi[64 + u * 3 + 2] * wv;
    }

    float att[16];
#pragma unroll
    for (int a = 0; a < 16; ++a) att[a] = hb[128 + a];

    for (int u = 0; u < 32; ++u) {
        const float* Wsp = &Wsc_s[u * 1024 + o];
        const float* Wvp = &Wsc_v[u * 512 + o];
        float t0 = 0.f, t1 = 0.f, tv = 0.f;
#pragma unroll
        for (int a = 0; a < 16; ++a) {
            float aa = att[a];
            t0 += aa * Wsp[a * 64];
            t1 += aa * Wsp[a * 64 + 32];
            tv += aa * Wvp[a * 32];
        }
        float su = hb[u];
        ys0 += su * t0;
        ys1 += su * t1;
        float vv0 = hb[32 + u * 3 + 0];
        float vv1 = hb[32 + u * 3 + 1];
        float vv2 = hb[32 + u * 3 + 2];
        yv0 += vv0 * tv;
        yv1 += vv1 * tv;
        yv2 += vv2 * tv;
    }

    float os   = silu_f(ys0);
    float gate = silu_f(ys1);
    long base = (long)n * 128;
    out[base + o] = hb[o] + os;
    out[base + 32 + o * 3 + 0] = hb[32 + o * 3 + 0] + yv0 * gate;
    out[base + 32 + o * 3 + 1] = hb[32 + o * 3 + 1] + yv1 * gate;
    out[base + 32 + o * 3 + 2] = hb[32 + o * 3 + 2] + yv2 * gate;
}

// ---------------------------------------------------------------------------
extern "C" void kernel_launch(void* const* d_in, const int* in_sizes, int n_in,
                              void* d_out, int out_size, void* d_ws, size_t ws_size,
                              hipStream_t stream) {
    const float* node_feats     = (const float*)d_in[0];
    const float* node_attrs     = (const float*)d_in[1];
    const float* edge_embedding = (const float*)d_in[2];
    const float* edge_attrs     = (const float*)d_in[3];
    const int*   edge_src       = (const int*)d_in[4];
    const int*   edge_dst       = (const int*)d_in[5];
    const float* W1_s  = (const float*)d_in[6];
    const float* W1_v  = (const float*)d_in[7];
    const float* fc_w1 = (const float*)d_in[8];
    const float* fc_b1 = (const float*)d_in[9];
    const float* fc_w2 = (const float*)d_in[10];
    const float* W2_s  = (const float*)d_in[11];
    const float* W2_v  = (const float*)d_in[12];
    const float* Wsc_s = (const float*)d_in[13];
    const float* Wsc_v = (const float*)d_in[14];
    float* out = (float*)d_out;

    float* ws  = (float*)d_ws;
    float* xf  = ws;                       // NN*32 float4 = NN*128 floats
    int* ibase    = (int*)(ws + (long)NN * 128);
    int* counts   = ibase;                 // NN
    int* row_ptr  = ibase + NN;            // NN+1
    int* cursor   = ibase + 2 * NN + 1;    // NN
    int* edge_ids = ibase + 3 * NN + 1;    // NE

    hipMemsetAsync(counts, 0, (size_t)NN * sizeof(int), stream);
    k_hist<<<(NE + 255) / 256, 256, 0, stream>>>(edge_dst, counts);
    k_node_transform<<<(NN + 7) / 8, 256, 0, stream>>>(node_feats, W1_s, W1_v, xf);
    k_scan<<<1, 1024, 0, stream>>>(counts, row_ptr, cursor);
    k_fill<<<(NE + 255) / 256, 256, 0, stream>>>(edge_dst, cursor, edge_ids);
    k_gather_t<<<NN / 8, 256, 0, stream>>>(edge_embedding, edge_attrs, edge_src,
                                           fc_w1, fc_b1, fc_w2, xf,
                                           row_ptr, edge_ids,
                                           node_feats, node_attrs,
                                           W2_s, W2_v, Wsc_s, Wsc_v, out);
}

// Round 6
// 807.282 us; speedup vs baseline: 2.0453x; 1.1416x over previous
//
#include <hip/hip_runtime.h>

#define NN 50000
#define NE 800000
// NN % 8 == 0 -> grid NN/8, 8 nodes/block, NO early returns (post-loop barrier)

typedef _Float16 half2t __attribute__((ext_vector_type(2)));
union H16 { float4 f; half2t p[4]; };   // one 16B LDS read = 8 halves = 4 pairs

__device__ __forceinline__ float silu_f(float x) { return x / (1.0f + __expf(-x)); }

__device__ __forceinline__ float fdot2(half2t a, half2t b, float c) {
#if __has_builtin(__builtin_amdgcn_fdot2)
    return __builtin_amdgcn_fdot2(a, b, c, false);
#else
    return c + (float)a.x * (float)b.x + (float)a.y * (float)b.y;
#endif
}

// ---------------------------------------------------------------------------
// K1: xf[n][o] = float4( (s@W1_s)[o], xv0[o], xv1[o], xv2[o] )
// ---------------------------------------------------------------------------
__global__ __launch_bounds__(256) void k_node_transform(
    const float* __restrict__ node_feats,
    const float* __restrict__ W1_s,
    const float* __restrict__ W1_v,
    float* __restrict__ xf)
{
    __shared__ float sW1s[32 * 32];
    __shared__ float sW1v[32 * 32];
    __shared__ float sfeat[8][128];
    int t = threadIdx.x;
    for (int i = t; i < 1024; i += 256) { sW1s[i] = W1_s[i]; sW1v[i] = W1_v[i]; }
    int nodeBase = blockIdx.x * 8;
    for (int i = t; i < 8 * 128; i += 256) {
        int nn = nodeBase + (i >> 7);
        sfeat[i >> 7][i & 127] = (nn < NN) ? node_feats[(long)nn * 128 + (i & 127)] : 0.0f;
    }
    __syncthreads();
    int g = t >> 5, o = t & 31;
    int n = nodeBase + g;
    if (n >= NN) return;
    float accs = 0.f, acc0 = 0.f, acc1 = 0.f, acc2 = 0.f;
#pragma unroll
    for (int u = 0; u < 32; ++u) {
        float su  = sfeat[g][u];
        float vu0 = sfeat[g][32 + u * 3 + 0];
        float vu1 = sfeat[g][32 + u * 3 + 1];
        float vu2 = sfeat[g][32 + u * 3 + 2];
        float ws = sW1s[u * 32 + o];
        float wv = sW1v[u * 32 + o];
        accs += su * ws;
        acc0 += vu0 * wv;
        acc1 += vu1 * wv;
        acc2 += vu2 * wv;
    }
    float4 r; r.x = accs; r.y = acc0; r.z = acc1; r.w = acc2;
    *(float4*)&xf[((long)n * 32 + o) * 4] = r;
}

// ---------------------------------------------------------------------------
// CSR build: histogram -> single-block scan -> fill
// ---------------------------------------------------------------------------
__global__ __launch_bounds__(256) void k_hist(const int* __restrict__ edge_dst,
                                              int* __restrict__ counts)
{
    int e = blockIdx.x * 256 + threadIdx.x;
    if (e < NE) atomicAdd(&counts[edge_dst[e]], 1);
}

__global__ __launch_bounds__(1024) void k_scan(const int* __restrict__ counts,
                                               int* __restrict__ row_ptr,
                                               int* __restrict__ cursor)
{
    __shared__ int wsum[16];
    __shared__ int carry_s;
    int t = threadIdx.x;
    int lane = t & 63, w = t >> 6;
    if (t == 0) carry_s = 0;
    __syncthreads();
    for (int base = 0; base < NN; base += 1024) {
        int i = base + t;
        int v = (i < NN) ? counts[i] : 0;
        int s = v;
#pragma unroll
        for (int d = 1; d < 64; d <<= 1) {
            int o = __shfl_up(s, d, 64);
            if (lane >= d) s += o;
        }
        if (lane == 63) wsum[w] = s;
        __syncthreads();
        if (w == 0) {
            int ws = (lane < 16) ? wsum[lane] : 0;
#pragma unroll
            for (int d = 1; d < 16; d <<= 1) {
                int o = __shfl_up(ws, d, 64);
                if (lane >= d) ws += o;
            }
            if (lane < 16) wsum[lane] = ws;
        }
        __syncthreads();
        int excl = (s - v) + ((w > 0) ? wsum[w - 1] : 0) + carry_s;
        if (i < NN) { row_ptr[i] = excl; cursor[i] = excl; }
        int total = wsum[15];
        __syncthreads();
        if (t == 0) carry_s += total;
        __syncthreads();
    }
    if (t == 0) row_ptr[NN] = carry_s;
}

__global__ __launch_bounds__(256) void k_fill(const int* __restrict__ edge_dst,
                                              int* __restrict__ cursor,
                                              int* __restrict__ edge_ids)
{
    int e = blockIdx.x * 256 + threadIdx.x;
    if (e < NE) {
        int slot = atomicAdd(&cursor[edge_dst[e]], 1);
        edge_ids[slot] = e;
    }
}

// ---------------------------------------------------------------------------
// k_gather_t: fused per-dst-node kernel (edge MLP + messages + epilogue).
// block = 256 = 8 groups x 32 lanes, group = one node, 8-edge inner blocking.
//
// GEMV in f16 (f32 accumulate via v_dot2_f32_f16):
//  - sw2h [160][72] halves (stride 144B = 36 dw): lane l starts bank (4l)%32
//    -> per-8-lane perfect 4-bank partition, b128 at the 4-cyc floor
//  - hh: lane computes h[2l], h[2l+1] -> one packed ds_write_b32 per edge;
//    GEMV reads h as group-uniform broadcast b128 (8 halves)
//  - per 8-edge iter: 40 weight-b128 + 64 broadcast h-b128 (was 288 b128
//    per 8 edges in R5) and 1280 fdot2 (2 MAC each -> GEMV VALU halved)
// LDS pool 31.25 KB (sw2h 23K + hh 8K), epilogue scratch aliased after the
// block-wide barrier (NN%8==0 -> all threads reach it).
// __launch_bounds__(256,4): 4 blocks/CU target; est. ~110 live VGPR.
// Spill watch: WRITE_SIZE must stay at 25000 KB.
// ---------------------------------------------------------------------------
#define SW2_HBYTES (160 * 72 * 2)          // 23040
#define POOL_BYTES (SW2_HBYTES + 8 * 8 * 128)  // + hh 8KB = 31232

__global__ __launch_bounds__(256, 4) void k_gather_t(
    const float* __restrict__ edge_embedding,
    const float* __restrict__ edge_attrs,
    const int*   __restrict__ edge_src,
    const float* __restrict__ fc_w1,
    const float* __restrict__ fc_b1,
    const float* __restrict__ fc_w2,
    const float* __restrict__ xf,
    const int*   __restrict__ row_ptr,
    const int*   __restrict__ edge_ids,
    const float* __restrict__ node_feats,
    const float* __restrict__ node_attrs,
    const float* __restrict__ W2_s,
    const float* __restrict__ W2_v,
    const float* __restrict__ Wsc_s,
    const float* __restrict__ Wsc_v,
    float* __restrict__ out)
{
    __shared__ __align__(16) unsigned char pool[POOL_BYTES];
    _Float16* swp = (_Float16*)pool;                       // [160][72] halves
    half2t*   hhp = (half2t*)(pool + SW2_HBYTES);          // [8g][8e][32] pairs

    int t = threadIdx.x;
    // stage fc_w2 -> f16 transposed: swp[c*72 + j] = fc_w2[j*160 + c]
    for (int i = t; i < 64 * 160; i += 256) {
        int j = i / 160, c = i - j * 160;
        swp[c * 72 + j] = (_Float16)fc_w2[i];
    }
    __syncthreads();

    int g = t >> 5, lane = t & 31;
    int n = blockIdx.x * 8 + g;          // NN % 8 == 0: always < NN

    // first-layer weights for j = 2*lane, 2*lane+1 (register-resident)
    float w1a[8], w1b[8];
#pragma unroll
    for (int q = 0; q < 8; ++q) {
        w1a[q] = fc_w1[q * 64 + 2 * lane];
        w1b[q] = fc_w1[q * 64 + 2 * lane + 1];
    }
    float b1a = fc_b1[2 * lane], b1b = fc_b1[2 * lane + 1];

    int start = row_ptr[n];
    int end   = row_ptr[n + 1];

    float as0 = 0.f, as1 = 0.f;
    float av[9];
#pragma unroll
    for (int p = 0; p < 9; ++p) av[p] = 0.f;

    const float4* xf4 = (const float4*)xf;
    half2t* hme = hhp + g * (8 * 32);    // this group's h block
    const float INV_SQRT3 = 0.5773502691896258f;
    const float INV_SQRT2 = 0.7071067811865476f;
    const float INV_NEI   = 0.25f;

    for (int i0 = start; i0 < end; i0 += 8) {
        int ne = end - i0;               // >= 1
        int eid[8];
#pragma unroll
        for (int k = 0; k < 8; ++k) eid[k] = edge_ids[(k < ne) ? (i0 + k) : i0];

        // ---- hidden layer: h[2l],h[2l+1] per edge, packed half2 -> LDS
#pragma unroll
        for (int k = 0; k < 8; ++k) {
            float4 e0 = *(const float4*)&edge_embedding[(long)eid[k] * 8];
            float4 e1 = *(const float4*)&edge_embedding[(long)eid[k] * 8 + 4];
            float h0 = b1a, h1 = b1b;
            h0 += e0.x * w1a[0] + e0.y * w1a[1] + e0.z * w1a[2] + e0.w * w1a[3];
            h0 += e1.x * w1a[4] + e1.y * w1a[5] + e1.z * w1a[6] + e1.w * w1a[7];
            h1 += e0.x * w1b[0] + e0.y * w1b[1] + e0.z * w1b[2] + e0.w * w1b[3];
            h1 += e1.x * w1b[4] + e1.y * w1b[5] + e1.z * w1b[6] + e1.w * w1b[7];
            half2t hp;
            hp.x = (_Float16)silu_f(h0);
            hp.y = (_Float16)silu_f(h1);
            hme[k * 32 + lane] = hp;
        }
        // same-wave LDS RAW (group-private): in-order DS pipe, no barrier

        // ---- w = h @ fc_w2 (f16 dot2, f32 acc), 8-edge register block
        float acc[5][8];
#pragma unroll
        for (int p = 0; p < 5; ++p)
#pragma unroll
            for (int k = 0; k < 8; ++k) acc[p][k] = 0.f;

#pragma unroll 2
        for (int jq = 0; jq < 8; ++jq) {           // 8 halves (8 j's) per step
            H16 w0, w1, w2, w3, w4;
            w0.f = *(const float4*)&swp[(0 * 32 + lane) * 72 + jq * 8];
            w1.f = *(const float4*)&swp[(1 * 32 + lane) * 72 + jq * 8];
            w2.f = *(const float4*)&swp[(2 * 32 + lane) * 72 + jq * 8];
            w3.f = *(const float4*)&swp[(3 * 32 + lane) * 72 + jq * 8];
            w4.f = *(const float4*)&swp[(4 * 32 + lane) * 72 + jq * 8];
#pragma unroll
            for (int k = 0; k < 8; ++k) {
                H16 hv;
                hv.f = *(const float4*)&hme[k * 32 + jq * 4];   // broadcast
#pragma unroll
                for (int m = 0; m < 4; ++m) {
                    acc[0][k] = fdot2(hv.p[m], w0.p[m], acc[0][k]);
                    acc[1][k] = fdot2(hv.p[m], w1.p[m], acc[1][k]);
                    acc[2][k] = fdot2(hv.p[m], w2.p[m], acc[2][k]);
                    acc[3][k] = fdot2(hv.p[m], w3.p[m], acc[3][k]);
                    acc[4][k] = fdot2(hv.p[m], w4.p[m], acc[4][k]);
                }
            }
        }

        // ---- messages, 2 sub-blocks of 4 (bounded preload register cost)
#pragma unroll
        for (int h0i = 0; h0i < 8; h0i += 4) {
            if (h0i >= ne) break;
            int srcv[4];
#pragma unroll
            for (int k = 0; k < 4; ++k) srcv[k] = edge_src[eid[h0i + k]];
            float4 at[4], xv[4];
#pragma unroll
            for (int k = 0; k < 4; ++k) {
                at[k] = *(const float4*)&edge_attrs[(long)eid[h0i + k] * 4];
                xv[k] = xf4[(long)srcv[k] * 32 + lane];
            }
#pragma unroll
            for (int k = 0; k < 4; ++k) {
                int kk = h0i + k;
                if (kk >= ne) break;
                float4 a4 = at[k];
                float xs  = xv[k].x;
                float xv0 = xv[k].y, xv1 = xv[k].z, xv2 = xv[k].w;
                float w00 = acc[0][kk], w01 = acc[1][kk], w10 = acc[2][kk];
                float w11s = acc[3][kk], w11v = acc[4][kk];

                as0 += w00 * xs * a4.x;
                float dot = xv0 * a4.y + xv1 * a4.z + xv2 * a4.w;
                as1 += w11s * dot * INV_SQRT3;
                float t01 = w01 * xs;
                av[0] += t01 * a4.y; av[1] += t01 * a4.z; av[2] += t01 * a4.w;
                float t10 = w10 * a4.x;
                av[3] += t10 * xv0; av[4] += t10 * xv1; av[5] += t10 * xv2;
                float k2 = w11v * INV_SQRT2;
                av[6] += k2 * (xv1 * a4.w - xv2 * a4.z);
                av[7] += k2 * (xv2 * a4.y - xv0 * a4.w);
                av[8] += k2 * (xv0 * a4.z - xv1 * a4.y);
            }
        }
    }

    // ---- weights dead; alias pool as epilogue scratch (all threads arrive)
    __syncthreads();
    float* epi = (float*)pool + (g << 9);   // 512 f32/group:
    // [0:64) as | [64:352) av | [352:480) feats | [480:496) attrs

    epi[lane]      = as0 * INV_NEI;
    epi[32 + lane] = as1 * INV_NEI;
#pragma unroll
    for (int p = 0; p < 3; ++p)
#pragma unroll
        for (int c = 0; c < 3; ++c)
            epi[64 + (p * 32 + lane) * 3 + c] = av[p * 3 + c] * INV_NEI;

    *(float4*)&epi[352 + lane * 4] = *(const float4*)&node_feats[(long)n * 128 + lane * 4];
    if (lane < 16) epi[480 + lane] = node_attrs[(long)n * 16 + lane];

    // ---- fused epilogue: W2 GEMVs + Wsc bilinear (t-form) + gate + residual
    int o = lane;
    float ys0 = 0.f, ys1 = 0.f, yv0 = 0.f, yv1 = 0.f, yv2 = 0.f;

#pragma unroll 8
    for (int u = 0; u < 64; ++u) {
        float as = epi[u];
        ys0 += as * W2_s[u * 64 + o];
        ys1 += as * W2_s[u * 64 + 32 + o];
    }
#pragma unroll 8
    for (int u = 0; u < 96; ++u) {
        float wv = W2_v[u * 32 + o];
        yv0 += epi[64 + u * 3 + 0] * wv;
        yv1 += epi[64 + u * 3 + 1] * wv;
        yv2 += epi[64 + u * 3 + 2] * wv;
    }

    float att[16];
#pragma unroll
    for (int a = 0; a < 16; ++a) att[a] = epi[480 + a];

    for (int u = 0; u < 32; ++u) {
        const float* Wsp = &Wsc_s[u * 1024 + o];
        const float* Wvp = &Wsc_v[u * 512 + o];
        float t0 = 0.f, t1 = 0.f, tv = 0.f;
#pragma unroll
        for (int a = 0; a < 16; ++a) {
            float aa = att[a];
            t0 += aa * Wsp[a * 64];
            t1 += aa * Wsp[a * 64 + 32];
            tv += aa * Wvp[a * 32];
        }
        float su = epi[352 + u];
        ys0 += su * t0;
        ys1 += su * t1;
        yv0 += epi[352 + 32 + u * 3 + 0] * tv;
        yv1 += epi[352 + 32 + u * 3 + 1] * tv;
        yv2 += epi[352 + 32 + u * 3 + 2] * tv;
    }

    float os   = silu_f(ys0);
    float gate = silu_f(ys1);
    long base = (long)n * 128;
    out[base + o] = epi[352 + o] + os;
    out[base + 32 + o * 3 + 0] = epi[352 + 32 + o * 3 + 0] + yv0 * gate;
    out[base + 32 + o * 3 + 1] = epi[352 + 32 + o * 3 + 1] + yv1 * gate;
    out[base + 32 + o * 3 + 2] = epi[352 + 32 + o * 3 + 2] + yv2 * gate;
}

// ---------------------------------------------------------------------------
extern "C" void kernel_launch(void* const* d_in, const int* in_sizes, int n_in,
                              void* d_out, int out_size, void* d_ws, size_t ws_size,
                              hipStream_t stream) {
    const float* node_feats     = (const float*)d_in[0];
    const float* node_attrs     = (const float*)d_in[1];
    const float* edge_embedding = (const float*)d_in[2];
    const float* edge_attrs     = (const float*)d_in[3];
    const int*   edge_src       = (const int*)d_in[4];
    const int*   edge_dst       = (const int*)d_in[5];
    const float* W1_s  = (const float*)d_in[6];
    const float* W1_v  = (const float*)d_in[7];
    const float* fc_w1 = (const float*)d_in[8];
    const float* fc_b1 = (const float*)d_in[9];
    const float* fc_w2 = (const float*)d_in[10];
    const float* W2_s  = (const float*)d_in[11];
    const float* W2_v  = (const float*)d_in[12];
    const float* Wsc_s = (const float*)d_in[13];
    const float* Wsc_v = (const float*)d_in[14];
    float* out = (float*)d_out;

    float* ws  = (float*)d_ws;
    float* xf  = ws;                       // NN*32 float4 = NN*128 floats
    int* ibase    = (int*)(ws + (long)NN * 128);
    int* counts   = ibase;                 // NN
    int* row_ptr  = ibase + NN;            // NN+1
    int* cursor   = ibase + 2 * NN + 1;    // NN
    int* edge_ids = ibase + 3 * NN + 1;    // NE

    hipMemsetAsync(counts, 0, (size_t)NN * sizeof(int), stream);
    k_hist<<<(NE + 255) / 256, 256, 0, stream>>>(edge_dst, counts);
    k_node_transform<<<(NN + 7) / 8, 256, 0, stream>>>(node_feats, W1_s, W1_v, xf);
    k_scan<<<1, 1024, 0, stream>>>(counts, row_ptr, cursor);
    k_fill<<<(NE + 255) / 256, 256, 0, stream>>>(edge_dst, cursor, edge_ids);
    k_gather_t<<<NN / 8, 256, 0, stream>>>(edge_embedding, edge_attrs, edge_src,
                                           fc_w1, fc_b1, fc_w2, xf,
                                           row_ptr, edge_ids,
                                           node_feats, node_attrs,
                                           W2_s, W2_v, Wsc_s, Wsc_v, out);
}